// Round 15
// baseline (256.563 us; speedup 1.0000x reference)
//
#include <hip/hip_runtime.h>
#include <cstdint>

#define BATCH 4
#define TQ 256
#define TK 256
#define DIM 256
#define HD 256

typedef _Float16 f16x8 __attribute__((ext_vector_type(8)));
typedef float f32x4 __attribute__((ext_vector_type(4)));

union U4H8 { uint4 u; f16x8 v; };

// Opaque def+use: forces the value to be materialized in a VGPR here and
// prevents the compiler from sinking/rematerializing the producing load.
#define KEEP(x) asm volatile("" : "+v"(x))

__device__ __forceinline__ unsigned short f2h(float f) {
    _Float16 h = (_Float16)f;
    unsigned short u;
    __builtin_memcpy(&u, &h, 2);
    return u;
}

__device__ __forceinline__ f16x8 relu8(f16x8 h) {
    f16x8 z = {};
#if __has_builtin(__builtin_elementwise_max)
    return __builtin_elementwise_max(h, z);
#else
#pragma unroll
    for (int i = 0; i < 8; ++i) h[i] = h[i] > (_Float16)0 ? h[i] : (_Float16)0;
    return h;
#endif
}

// R15: SINGLE-LAUNCH fusion. 256 blocks (= #CUs, all resident: 47KB LDS,
// >=2 slots/CU -> spin barrier cannot starve), 256 threads / 4 waves.
// Phase 1: prep (W2T row + 4 qh rows + 4 kh rows per block, f16 out).
// Phase 2: device-wide software barrier (device-scope atomic + threadfence
// for cross-XCD L2 visibility; counter zeroed by hipMemsetAsync pre-launch).
// Phase 3: TWO R11 attn tasks per block (R11 = 50.6us champion, verbatim:
// single-buffer Afrag, T14 reg-held staging, swapped-operand MFMA with
// A=W2T pinned 128 regs/wave, lane-local n-reduce, atomic-free sprt).
// Tasks are batch-rotated so each block gets two different batches
// (flattens klen imbalance). Removes one kernel launch + inter-kernel gap,
// and loads the W2T pin once for both tasks.
__global__ __launch_bounds__(256, 2) void fused_all(
    const float* __restrict__ queries, const float* __restrict__ keys,
    const float* __restrict__ W1, const float* __restrict__ b1,
    const float* __restrict__ W2, const float* __restrict__ b2,
    const float* __restrict__ W3,
    const int* __restrict__ qlens, const int* __restrict__ klens,
    unsigned short* __restrict__ qhh, unsigned short* __restrict__ khh,
    unsigned short* __restrict__ W2T, unsigned int* __restrict__ gbar,
    float* __restrict__ out) {
    int i = blockIdx.x;
    int t = threadIdx.x;
    int w = t >> 6, lane = t & 63;
    int col = lane & 15, quad = lane >> 4;

    __shared__ float4 xs4[4][DIM / 4];    // 4KB  (prep)
    __shared__ uint4 Afrag[8][4][64];     // 32KB (attn, single buffer)
    __shared__ float sprt[4][2][TK];      // 8KB
    __shared__ float srow[2][TK];         // 2KB
    __shared__ uint4 qbuf4[2][HD / 8];    // 1KB
    __shared__ float red[16];

    // ================= Phase 1: prep =================
    // W2T row i: W2T[i][c] = (f16)W2[c][i]  (write coalesced, read via L2)
    W2T[(size_t)i * HD + t] = f2h(W2[(size_t)t * HD + i]);

    // qh rows i*4..+3 (pass 0, +b1) and kh rows i*4..+3 (pass 1)
#pragma unroll 1
    for (int pass = 0; pass < 2; ++pass) {
        bool isQ = (pass == 0);
        const float* X = isQ ? queries : keys;
        const float* W = W1 + (isQ ? DIM * HD : 0);
        unsigned short* O = isQ ? qhh : khh;
        int r0 = i * 4;
        xs4[t >> 6][t & 63] =
            *(const float4*)(X + (size_t)(r0 + (t >> 6)) * DIM + (t & 63) * 4);
        __syncthreads();
        float acc[4] = {0.f, 0.f, 0.f, 0.f};
#pragma unroll 4
        for (int d4 = 0; d4 < DIM / 4; ++d4) {
            const float4 x0 = xs4[0][d4];
            const float4 x1 = xs4[1][d4];
            const float4 x2 = xs4[2][d4];
            const float4 x3 = xs4[3][d4];
            const float w0 = W[(d4 * 4 + 0) * HD + t];   // coalesced across t
            const float w1 = W[(d4 * 4 + 1) * HD + t];
            const float w2 = W[(d4 * 4 + 2) * HD + t];
            const float w3 = W[(d4 * 4 + 3) * HD + t];
            acc[0] = fmaf(x0.x, w0, acc[0]); acc[1] = fmaf(x1.x, w0, acc[1]);
            acc[2] = fmaf(x2.x, w0, acc[2]); acc[3] = fmaf(x3.x, w0, acc[3]);
            acc[0] = fmaf(x0.y, w1, acc[0]); acc[1] = fmaf(x1.y, w1, acc[1]);
            acc[2] = fmaf(x2.y, w1, acc[2]); acc[3] = fmaf(x3.y, w1, acc[3]);
            acc[0] = fmaf(x0.z, w2, acc[0]); acc[1] = fmaf(x1.z, w2, acc[1]);
            acc[2] = fmaf(x2.z, w2, acc[2]); acc[3] = fmaf(x3.z, w2, acc[3]);
            acc[0] = fmaf(x0.w, w3, acc[0]); acc[1] = fmaf(x1.w, w3, acc[1]);
            acc[2] = fmaf(x2.w, w3, acc[2]); acc[3] = fmaf(x3.w, w3, acc[3]);
        }
        float bias = isQ ? b1[t] : 0.f;
#pragma unroll
        for (int r = 0; r < 4; ++r)
            O[(size_t)(r0 + r) * HD + t] = f2h(acc[r] + bias);
        __syncthreads();   // xs4 reuse guard
    }

    // ============ Phase 2: device-wide barrier ============
    // All 256 blocks are resident (grid == #CUs, >=2 slots/CU) -> no deadlock.
    if (t == 0) {
        __threadfence();                      // release our prep stores (L2 wb)
        atomicAdd(gbar, 1u);                  // device-scope arrival
        while (atomicAdd(gbar, 0u) < 256u)    // device-scope coherent read
            __builtin_amdgcn_s_sleep(8);
    }
    __syncthreads();
    __threadfence();                          // acquire: invalidate stale L1/L2

    // ===== W2T slice pin: loaded ONCE for both tasks (R11 formulas) =====
    int nb = w << 6;
    uint4 bfr[4][8];
#pragma unroll
    for (int nt = 0; nt < 4; ++nt) {
        int n = nb + (nt << 4) + col;
        const uint4* r = (const uint4*)(W2T + n * HD) + quad;  // quad -> h-octet
#pragma unroll
        for (int s = 0; s < 8; ++s) bfr[nt][s] = r[s * 4];
    }
    float b2v[4][4], w3v[4][4];
#pragma unroll
    for (int nt = 0; nt < 4; ++nt)
#pragma unroll
        for (int r = 0; r < 4; ++r) {
            int n = nb + (nt << 4) + (quad << 2) + r;
            b2v[nt][r] = b2[n];
            w3v[nt][r] = W3[n];
        }
#pragma unroll
    for (int nt = 0; nt < 4; ++nt)
#pragma unroll
        for (int s = 0; s < 8; ++s) {
            KEEP(bfr[nt][s].x); KEEP(bfr[nt][s].y);
            KEEP(bfr[nt][s].z); KEEP(bfr[nt][s].w);
        }

    int qsel = w >> 1;
    int rsub = ((w & 1) << 4) | col;

    // ============ Phase 3: two R11 attn tasks ============
#pragma unroll 1
    for (int g = 0; g < 2; ++g) {
        // batch-rotated bijective pairing: task0 = i (batch i&3),
        // task1 = 256 + (i&~3) + ((i+1)&3) (batch (i+1)&3) -> balanced klen.
        int task = (g == 0) ? i : (256 + (i & ~3) + ((i + 1) & 3));
        int b = task & 3;
        int q0 = (task >> 2) << 1;
        int qlen = qlens[b];
        float* orow = out + ((size_t)b * TQ + q0) * DIM;
        if (q0 >= qlen) {
            orow[t] = 0.f; orow[DIM + t] = 0.f;   // block-uniform skip
        } else {
            bool v1 = (q0 + 1) < qlen;
            int klen = klens[b];
            int nch = (klen + 31) >> 5;   // 4..8 chunks of 32 k
            const unsigned short* kbase =
                khh + ((size_t)b * TK + rsub) * HD + (quad << 3);

            // q-pair rows -> LDS (f16, 64 uint4)
            if (t < 64)
                qbuf4[t >> 5][t & 31] = *(const uint4*)(
                    qhh + (size_t)(b * TQ + q0 + (t >> 5)) * HD + (t & 31) * 8);

            // prologue: stage chunk 0 (k and q from global)
            {
                const unsigned short* qrowg =
                    qhh + (size_t)(b * TQ + q0 + qsel) * HD + (quad << 3);
                uint4* as = &Afrag[0][w][lane];
#pragma unroll
                for (int s = 0; s < 8; ++s) {
                    U4H8 kf, qf, h;
                    kf.u = *(const uint4*)(kbase + s * 32);
                    qf.u = *(const uint4*)(qrowg + s * 32);
                    h.v = relu8(kf.v + qf.v);
                    as[s * 256] = h.u;   // s-stride = 4*64 uint4
                }
            }
            __syncthreads();      // chunk 0 staged, qbuf ready

            for (int c = 0; c < nch; ++c) {
                bool stg = (c + 1 < nch);
                const unsigned short* krow = kbase + (((c + 1) << 5)) * HD;
                uint4 Kst[8];
                if (stg) {   // T14: issue next chunk's 8 K-octet loads NOW
#pragma unroll
                    for (int s = 0; s < 8; ++s)
                        Kst[s] = *(const uint4*)(krow + s * 32);
#pragma unroll
                    for (int s = 0; s < 8; ++s) {
                        KEEP(Kst[s].x); KEEP(Kst[s].y);
                        KEEP(Kst[s].z); KEEP(Kst[s].w);
                    }
                }
                __builtin_amdgcn_sched_barrier(0);  // loads stay above MFMAs

#pragma unroll
                for (int mt = 0; mt < 4; ++mt) {
                    f32x4 acc[4] = {};
#pragma unroll
                    for (int s = 0; s < 8; ++s) {
                        U4H8 au;
                        au.u = Afrag[s][mt][lane];
#pragma unroll
                        for (int nt = 0; nt < 4; ++nt) {
                            U4H8 bu;
                            bu.u = bfr[nt][s];
                            acc[nt] = __builtin_amdgcn_mfma_f32_16x16x32_f16(
                                bu.v, au.v, acc[nt], 0, 0, 0);   // A=W2T, B=H
                        }
                    }
                    // lane-local n-reduce, 2-stage quad reduce, 1 b32 write
                    float part = 0.f;
#pragma unroll
                    for (int nt = 0; nt < 4; ++nt)
#pragma unroll
                        for (int r = 0; r < 4; ++r)
                            part = fmaf(fmaxf(acc[nt][r] + b2v[nt][r], 0.f),
                                        w3v[nt][r], part);
                    part += __shfl_xor(part, 16, 64);
                    part += __shfl_xor(part, 32, 64);
                    if (quad == 0)
                        sprt[w][mt >> 1][(c << 5) | ((mt & 1) << 4) | col] = part;
                }

                __syncthreads();   // all reads of Afrag complete
                if (stg) {         // write next chunk (vmcnt met long ago)
                    uint4* as = &Afrag[0][w][lane];
#pragma unroll
                    for (int s = 0; s < 8; ++s) {
                        U4H8 kf, qf, h;
                        kf.u = Kst[s];
                        qf.u = qbuf4[qsel][s * 4 + quad];   // broadcast read
                        h.v = relu8(kf.v + qf.v);
                        as[s * 256] = h.u;
                    }
                }
                __syncthreads();   // next chunk visible
            }

            // masked softmax over both score rows (sum the 4 wave partials)
            float s0 = -3.4e38f, s1 = -3.4e38f;
            if (t < klen) {
                s0 = (sprt[0][0][t] + sprt[1][0][t]) +
                     (sprt[2][0][t] + sprt[3][0][t]);
                s1 = (sprt[0][1][t] + sprt[1][1][t]) +
                     (sprt[2][1][t] + sprt[3][1][t]);
            }
            float m0 = s0, m1 = s1;
#pragma unroll
            for (int off = 1; off < 64; off <<= 1) {
                m0 = fmaxf(m0, __shfl_xor(m0, off, 64));
                m1 = fmaxf(m1, __shfl_xor(m1, off, 64));
            }
            if (lane == 0) { red[w] = m0; red[8 + w] = m1; }
            __syncthreads();
            m0 = fmaxf(fmaxf(red[0], red[1]), fmaxf(red[2], red[3]));
            m1 = fmaxf(fmaxf(red[8], red[9]), fmaxf(red[10], red[11]));
            float e0 = (t < klen) ? __expf(s0 - m0) : 0.f;
            float e1 = (t < klen) ? __expf(s1 - m1) : 0.f;
            float u0 = e0, u1 = e1;
#pragma unroll
            for (int off = 1; off < 64; off <<= 1) {
                u0 += __shfl_xor(u0, off, 64);
                u1 += __shfl_xor(u1, off, 64);
            }
            if (lane == 0) { red[4 + w] = u0; red[12 + w] = u1; }
            __syncthreads();
            float d0 = red[4] + red[5] + red[6] + red[7];
            float d1 = red[12] + red[13] + red[14] + red[15];
            srow[0][t] = e0 / d0;   // probs q0
            srow[1][t] = e1 / d1;   // probs q0+1
            __syncthreads();

            // PV: both rows share each keys load; 16 loads in flight
            float a0 = 0.f, a1 = 0.f;
            const float* kp = keys + (size_t)b * TK * DIM + t;  // t = channel
#pragma unroll 16
            for (int k = 0; k < klen; ++k) {
                float v = kp[k * DIM];
                a0 = fmaf(srow[0][k], v, a0);
                a1 = fmaf(srow[1][k], v, a1);
            }
            orow[t] = a0;
            orow[DIM + t] = v1 ? a1 : 0.f;
        }
        __syncthreads();   // LDS (sprt/srow/qbuf/Afrag) free for next task
    }
}

extern "C" void kernel_launch(void* const* d_in, const int* in_sizes, int n_in,
                              void* d_out, int out_size, void* d_ws, size_t ws_size,
                              hipStream_t stream) {
    (void)in_sizes; (void)n_in; (void)out_size; (void)ws_size;
    const float* queries = (const float*)d_in[0];
    const float* keys    = (const float*)d_in[1];
    const int*   qlens   = (const int*)d_in[2];
    const int*   klens   = (const int*)d_in[3];
    const float* W1      = (const float*)d_in[4];
    const float* b1      = (const float*)d_in[5];
    const float* W2      = (const float*)d_in[6];
    const float* b2      = (const float*)d_in[7];
    const float* W3      = (const float*)d_in[8];
    float* out = (float*)d_out;

    unsigned short* qhh = (unsigned short*)d_ws;          // 512 KB f16 (b1 folded)
    unsigned short* khh = qhh + BATCH * TQ * HD;          // 512 KB f16
    unsigned short* W2T = khh + BATCH * TK * HD;          // 128 KB f16
    unsigned int* gbar = (unsigned int*)(W2T + HD * HD);  // barrier counter

    hipMemsetAsync(gbar, 0, sizeof(unsigned int), stream);  // stream-ordered
    fused_all<<<256, 256, 0, stream>>>(
        queries, keys, W1, b1, W2, b2, W3, qlens, klens,
        qhh, khh, W2T, gbar, out);
}

// Round 16
// 124.239 us; speedup vs baseline: 2.0651x; 2.0651x over previous
//
#include <hip/hip_runtime.h>
#include <cstdint>

#define BATCH 4
#define TQ 256
#define TK 256
#define DIM 256
#define HD 256

typedef _Float16 f16x8 __attribute__((ext_vector_type(8)));
typedef float f32x4 __attribute__((ext_vector_type(4)));

union U4H8 { uint4 u; f16x8 v; };

// Opaque def+use: forces the value to be materialized in a VGPR here and
// prevents the compiler from sinking/rematerializing the producing load.
#define KEEP(x) asm volatile("" : "+v"(x))

__device__ __forceinline__ unsigned short f2h(float f) {
    _Float16 h = (_Float16)f;
    unsigned short u;
    __builtin_memcpy(&u, &h, 2);
    return u;
}

__device__ __forceinline__ f16x8 relu8(f16x8 h) {
    f16x8 z = {};
#if __has_builtin(__builtin_elementwise_max)
    return __builtin_elementwise_max(h, z);
#else
#pragma unroll
    for (int i = 0; i < 8; ++i) h[i] = h[i] > (_Float16)0 ? h[i] : (_Float16)0;
    return h;
#endif
}

// Fused prep: blocks 0..511  -> qhh f16 = queries@W1[256:]+b1, khh f16 = keys@W1[:256]
//             blocks 512..575 -> W2T[n][c] = (f16)W2[c][n]
// (f16 qh/kh numerics validated: absmax unchanged at 0.00195.)
__global__ __launch_bounds__(256) void prep_all(
    const float* __restrict__ queries, const float* __restrict__ keys,
    const float* __restrict__ W1, const float* __restrict__ b1,
    const float* __restrict__ W2,
    unsigned short* __restrict__ qhh, unsigned short* __restrict__ khh,
    unsigned short* __restrict__ W2T) {
    int i = blockIdx.x;
    int t = threadIdx.x;
    if (i >= 512) {  // ---- W2 transpose ----
        __shared__ float tile[32][33];
        int bi = i - 512;
        int tx = t & 31, ty = t >> 5;
        int tc = (bi & 7) * 32, tn = (bi >> 3) * 32;
#pragma unroll
        for (int r = 0; r < 4; ++r)
            tile[ty + r * 8][tx] = W2[(tc + ty + r * 8) * HD + tn + tx];
        __syncthreads();
#pragma unroll
        for (int r = 0; r < 4; ++r)
            W2T[(tn + ty + r * 8) * HD + tc + tx] = f2h(tile[tx][ty + r * 8]);
        return;
    }
    // ---- qh / kh: 4 rows/block, 512 blocks ----
    bool isQ = i < 256;
    int r0 = (i & 255) * 4;
    const float* X = isQ ? queries : keys;
    const float* W = W1 + (isQ ? DIM * HD : 0);
    unsigned short* O = isQ ? qhh : khh;
    __shared__ float4 xs4[4][DIM / 4];   // 4 rows x 64 float4 = 4KB
    xs4[t >> 6][t & 63] =
        *(const float4*)(X + (size_t)(r0 + (t >> 6)) * DIM + (t & 63) * 4);
    __syncthreads();
    float acc[4] = {0.f, 0.f, 0.f, 0.f};
#pragma unroll 4
    for (int d4 = 0; d4 < DIM / 4; ++d4) {
        const float4 x0 = xs4[0][d4];
        const float4 x1 = xs4[1][d4];
        const float4 x2 = xs4[2][d4];
        const float4 x3 = xs4[3][d4];
        const float w0 = W[(d4 * 4 + 0) * HD + t];   // coalesced across t
        const float w1 = W[(d4 * 4 + 1) * HD + t];
        const float w2 = W[(d4 * 4 + 2) * HD + t];
        const float w3 = W[(d4 * 4 + 3) * HD + t];
        acc[0] = fmaf(x0.x, w0, acc[0]); acc[1] = fmaf(x1.x, w0, acc[1]);
        acc[2] = fmaf(x2.x, w0, acc[2]); acc[3] = fmaf(x3.x, w0, acc[3]);
        acc[0] = fmaf(x0.y, w1, acc[0]); acc[1] = fmaf(x1.y, w1, acc[1]);
        acc[2] = fmaf(x2.y, w1, acc[2]); acc[3] = fmaf(x3.y, w1, acc[3]);
        acc[0] = fmaf(x0.z, w2, acc[0]); acc[1] = fmaf(x1.z, w2, acc[1]);
        acc[2] = fmaf(x2.z, w2, acc[2]); acc[3] = fmaf(x3.z, w2, acc[3]);
        acc[0] = fmaf(x0.w, w3, acc[0]); acc[1] = fmaf(x1.w, w3, acc[1]);
        acc[2] = fmaf(x2.w, w3, acc[2]); acc[3] = fmaf(x3.w, w3, acc[3]);
    }
    float bias = isQ ? b1[t] : 0.f;
#pragma unroll
    for (int r = 0; r < 4; ++r)
        O[(size_t)(r0 + r) * HD + t] = f2h(acc[r] + bias);
}

// R16 = byte-exact revert to the R11 champion (best measured: mlp_attn
// 50.6us, total 125.5us). Session conclusion encoded here:
//  - 4 waves / 256 threads / 512 blocks (2 serialized generations) is the
//    empirical optimum; more TLP (R3/R12/R13) and fused single-launch (R15)
//    all regressed.
//  - LDS cut to 44.5KB (single-buffer Afrag + f16 qh/kh), T14 reg-held
//    next-chunk staging, swapped-operand MFMA (A=W2T pinned 128 regs/wave,
//    B=H) -> lane-local n-reduce, atomic-free sprt epilogue.
//  - Remaining total = ~60us fixed harness cost + ~10us prep + ~50us attn
//    latency floor (MfmaUtil ~15% with all pipes idle = dependency-chain
//    bound at 1 wave/SIMD; not a pipe roofline).
__global__ __launch_bounds__(256, 2) void mlp_attn(
    const unsigned short* __restrict__ qh, const unsigned short* __restrict__ kh,
    const unsigned short* __restrict__ W2T,
    const float* __restrict__ b2, const float* __restrict__ W3,
    const float* __restrict__ keys,
    const int* __restrict__ qlens, const int* __restrict__ klens,
    float* __restrict__ out) {
    int orig = blockIdx.x;
    // XCD-contiguous task range, batch-interleaved inside it.
    int task = ((orig & 7) << 6) | (orig >> 3);
    int b = task & 3;
    int q0 = (task >> 2) << 1;
    int t = threadIdx.x;
    int qlen = qlens[b];
    float* orow = out + ((size_t)b * TQ + q0) * DIM;   // row q0; row q0+1 at +DIM
    if (q0 >= qlen) { orow[t] = 0.f; orow[DIM + t] = 0.f; return; }  // uniform
    bool v1 = (q0 + 1) < qlen;
    int klen = klens[b];
    int nch = (klen + 31) >> 5;   // 4..8 valid 32-wide k chunks

    __shared__ uint4 Afrag[8][4][64];   // [k-step][m-tile][lane], 32KB single buf
    __shared__ float sprt[4][2][TK];    // per-wave score partials, 8KB
    __shared__ float srow[2][TK];       // probs (2 q rows), 2KB
    __shared__ uint4 qbuf4[2][HD / 8];  // q-pair rows f16, 1KB
    __shared__ float red[16];

    int w = t >> 6, lane = t & 63;
    int col = lane & 15, quad = lane >> 4;

    // ---- this wave's W2T slice: 32 x uint4 = 128 regs (unified file) ----
    int nb = w << 6;
    uint4 bfr[4][8];
#pragma unroll
    for (int nt = 0; nt < 4; ++nt) {
        int n = nb + (nt << 4) + col;
        const uint4* r = (const uint4*)(W2T + n * HD) + quad;  // quad -> h-octet
#pragma unroll
        for (int s = 0; s < 8; ++s) bfr[nt][s] = r[s * 4];
    }
    // b2/w3 for D rows (hidden-n): n = nb + nt*16 + quad*4 + r
    float b2v[4][4], w3v[4][4];
#pragma unroll
    for (int nt = 0; nt < 4; ++nt)
#pragma unroll
        for (int r = 0; r < 4; ++r) {
            int n = nb + (nt << 4) + (quad << 2) + r;
            b2v[nt][r] = b2[n];
            w3v[nt][r] = W3[n];
        }

    // staging role: wave w owns m-tile w: q-row w>>1, k-row (w&1)*16 + col,
    // h-octet quad*8 + s*32. Per slot the wave writes one contiguous 1KB
    // region -> bank-conflict-free.
    int qsel = w >> 1;
    int rsub = ((w & 1) << 4) | col;
    const unsigned short* kbase = kh + ((size_t)b * TK + rsub) * HD + (quad << 3);

    // q-pair rows -> LDS (f16, 64 uint4)
    if (t < 64)
        qbuf4[t >> 5][t & 31] =
            *(const uint4*)(qh + (size_t)(b * TQ + q0 + (t >> 5)) * HD + (t & 31) * 8);

    // ---- prologue: stage chunk 0 (k and q from global) ----
    {
        const unsigned short* qrowg = qh + ((size_t)b * TQ + q0 + qsel) * HD + (quad << 3);
        uint4* as = &Afrag[0][w][lane];
#pragma unroll
        for (int s = 0; s < 8; ++s) {
            U4H8 kf, qf, h;
            kf.u = *(const uint4*)(kbase + s * 32);
            qf.u = *(const uint4*)(qrowg + s * 32);
            h.v = relu8(kf.v + qf.v);
            as[s * 256] = h.u;   // s-stride = 4*64 uint4
        }
    }

    // Pin the A(W2T) slice: opaque-define, cannot be sunk/rematerialized.
#pragma unroll
    for (int nt = 0; nt < 4; ++nt)
#pragma unroll
        for (int s = 0; s < 8; ++s) {
            KEEP(bfr[nt][s].x); KEEP(bfr[nt][s].y);
            KEEP(bfr[nt][s].z); KEEP(bfr[nt][s].w);
        }

    __syncthreads();      // chunk 0 staged, qbuf ready

    // One MFMA pass over m-tile mt: A = W2T frag, B = H frag (swapped).
    auto sloop = [&](int mt, f32x4* acc) {
#pragma unroll
        for (int s = 0; s < 8; ++s) {
            U4H8 au;
            au.u = Afrag[s][mt][lane];
#pragma unroll
            for (int nt = 0; nt < 4; ++nt) {
                U4H8 bu;
                bu.u = bfr[nt][s];
                acc[nt] = __builtin_amdgcn_mfma_f32_16x16x32_f16(
                    bu.v, au.v, acc[nt], 0, 0, 0);   // A=W2T, B=H
            }
        }
    };
    // relu(+b2)*W3 lane-local over 16 n, 2-stage quad reduce, 1 b32 write.
    auto epi = [&](int c, int mt, const f32x4* acc) {
        int hf = mt >> 1, m2 = mt & 1;
        float part = 0.f;
#pragma unroll
        for (int nt = 0; nt < 4; ++nt)
#pragma unroll
            for (int r = 0; r < 4; ++r)
                part = fmaf(fmaxf(acc[nt][r] + b2v[nt][r], 0.f), w3v[nt][r], part);
        part += __shfl_xor(part, 16, 64);
        part += __shfl_xor(part, 32, 64);
        if (quad == 0)
            sprt[w][hf][(c << 5) | (m2 << 4) | col] = part;
    };

    for (int c = 0; c < nch; ++c) {
        bool stg = (c + 1 < nch);
        const unsigned short* krow = kbase + (((c + 1) << 5)) * HD;
        uint4 Kst[8];
        if (stg) {   // T14: issue next chunk's 8 K-octet loads NOW (8 uint4)
#pragma unroll
            for (int s = 0; s < 8; ++s) Kst[s] = *(const uint4*)(krow + s * 32);
#pragma unroll
            for (int s = 0; s < 8; ++s) {
                KEEP(Kst[s].x); KEEP(Kst[s].y); KEEP(Kst[s].z); KEEP(Kst[s].w);
            }
        }
        __builtin_amdgcn_sched_barrier(0);   // loads stay above the MFMAs

        {   f32x4 acc[4] = {}; sloop(0, acc); epi(c, 0, acc); }
        {   f32x4 acc[4] = {}; sloop(1, acc); epi(c, 1, acc); }
        {   f32x4 acc[4] = {}; sloop(2, acc); epi(c, 2, acc); }
        {   f32x4 acc[4] = {}; sloop(3, acc); epi(c, 3, acc); }

        __syncthreads();   // all reads of Afrag complete
        if (stg) {         // write next chunk (vmcnt met ~4 passes ago)
            uint4* as = &Afrag[0][w][lane];
#pragma unroll
            for (int s = 0; s < 8; ++s) {
                U4H8 kf, qf, h;
                kf.u = Kst[s];
                qf.u = qbuf4[qsel][s * 4 + quad];   // broadcast read
                h.v = relu8(kf.v + qf.v);
                as[s * 256] = h.u;
            }
        }
        __syncthreads();   // next chunk visible
    }

    // ---- masked softmax over both score rows (sum the 4 wave partials) ----
    float s0 = -3.4e38f, s1 = -3.4e38f;
    if (t < klen) {
        s0 = (sprt[0][0][t] + sprt[1][0][t]) + (sprt[2][0][t] + sprt[3][0][t]);
        s1 = (sprt[0][1][t] + sprt[1][1][t]) + (sprt[2][1][t] + sprt[3][1][t]);
    }
    float m0 = s0, m1 = s1;
#pragma unroll
    for (int off = 1; off < 64; off <<= 1) {
        m0 = fmaxf(m0, __shfl_xor(m0, off, 64));
        m1 = fmaxf(m1, __shfl_xor(m1, off, 64));
    }
    if (lane == 0) { red[w] = m0; red[8 + w] = m1; }
    __syncthreads();
    m0 = fmaxf(fmaxf(red[0], red[1]), fmaxf(red[2], red[3]));
    m1 = fmaxf(fmaxf(red[8], red[9]), fmaxf(red[10], red[11]));
    float e0 = (t < klen) ? __expf(s0 - m0) : 0.f;
    float e1 = (t < klen) ? __expf(s1 - m1) : 0.f;
    float u0 = e0, u1 = e1;
#pragma unroll
    for (int off = 1; off < 64; off <<= 1) {
        u0 += __shfl_xor(u0, off, 64);
        u1 += __shfl_xor(u1, off, 64);
    }
    if (lane == 0) { red[4 + w] = u0; red[12 + w] = u1; }
    __syncthreads();
    float d0 = red[4] + red[5] + red[6] + red[7];
    float d1 = red[12] + red[13] + red[14] + red[15];
    srow[0][t] = e0 / d0;   // probs q0
    srow[1][t] = e1 / d1;   // probs q0+1
    __syncthreads();

    // ---- PV: both rows share each keys load; 16 loads in flight ----
    float a0 = 0.f, a1 = 0.f;
    const float* kp = keys + (size_t)b * TK * DIM + t;  // coalesced: t = channel
#pragma unroll 16
    for (int k = 0; k < klen; ++k) {
        float v = kp[k * DIM];
        a0 = fmaf(srow[0][k], v, a0);
        a1 = fmaf(srow[1][k], v, a1);
    }
    orow[t] = a0;
    orow[DIM + t] = v1 ? a1 : 0.f;
}

extern "C" void kernel_launch(void* const* d_in, const int* in_sizes, int n_in,
                              void* d_out, int out_size, void* d_ws, size_t ws_size,
                              hipStream_t stream) {
    (void)in_sizes; (void)n_in; (void)out_size; (void)ws_size;
    const float* queries = (const float*)d_in[0];
    const float* keys    = (const float*)d_in[1];
    const int*   qlens   = (const int*)d_in[2];
    const int*   klens   = (const int*)d_in[3];
    const float* W1      = (const float*)d_in[4];
    const float* b1      = (const float*)d_in[5];
    const float* W2      = (const float*)d_in[6];
    const float* b2      = (const float*)d_in[7];
    const float* W3      = (const float*)d_in[8];
    float* out = (float*)d_out;

    unsigned short* qhh = (unsigned short*)d_ws;          // 512 KB f16 (b1 folded)
    unsigned short* khh = qhh + BATCH * TQ * HD;          // 512 KB f16
    unsigned short* W2T = khh + BATCH * TK * HD;          // 128 KB f16

    prep_all<<<576, 256, 0, stream>>>(queries, keys, W1, b1, W2, qhh, khh, W2T);
    mlp_attn<<<BATCH * TQ / 2, 256, 0, stream>>>(
        qhh, khh, W2T, b2, W3, keys, qlens, klens, out);
}